// Round 1
// baseline (3039.879 us; speedup 1.0000x reference)
//
#include <hip/hip_runtime.h>
#include <hip/hip_bf16.h>
#include <math.h>
#include <stdint.h>

#define BB 16
#define CC 128
#define HH 128
#define WW 128
#define GG 32
#define CPG 4          // CC/GG
#define EPSV 1e-5f
#define NEG 0.1f

#define TS 32          // spatial tile (32x32)
#define COB 16         // output channels per block
#define CK 8           // input-channel chunk staged in LDS

// ---------------- GroupNorm statistics: one block per (b,g) ----------------
__global__ __launch_bounds__(256)
void gn_stats_kernel(const float* __restrict__ x, float* __restrict__ stats) {
    const int bg = blockIdx.x;                 // 0..511
    const float* base = x + (size_t)bg * (CPG * HH * WW);   // 65536 contiguous
    float s1 = 0.f, s2 = 0.f;
    for (int i = threadIdx.x; i < 65536 / 4; i += 256) {
        float4 v = *(const float4*)&base[i * 4];
        s1 += v.x + v.y + v.z + v.w;
        s2 += v.x * v.x + v.y * v.y + v.z * v.z + v.w * v.w;
    }
    #pragma unroll
    for (int off = 32; off > 0; off >>= 1) {
        s1 += __shfl_down(s1, off);
        s2 += __shfl_down(s2, off);
    }
    __shared__ float rs[8];
    const int wid = threadIdx.x >> 6, lane = threadIdx.x & 63;
    if (lane == 0) { rs[wid * 2] = s1; rs[wid * 2 + 1] = s2; }
    __syncthreads();
    if (threadIdx.x == 0) {
        s1 = rs[0] + rs[2] + rs[4] + rs[6];
        s2 = rs[1] + rs[3] + rs[5] + rs[7];
        float mean = s1 * (1.f / 65536.f);
        float var  = s2 * (1.f / 65536.f) - mean * mean;
        stats[2 * bg]     = mean;
        stats[2 * bg + 1] = rsqrtf(var + EPSV);
    }
}

// ---------------- small FCs: tmp1 = leaky(k_v @ kW1^T); nfb = te @ nf_w^T + nf_b
__global__ __launch_bounds__(256)
void small1_kernel(const float* __restrict__ te, const float* __restrict__ nfw,
                   const float* __restrict__ nfbias, const float* __restrict__ kv,
                   const float* __restrict__ kw1,
                   float* __restrict__ nfb, float* __restrict__ tmp1) {
    const int idx = blockIdx.x * 256 + threadIdx.x;
    if (idx < 1024) {                       // tmp1: (16,64)
        const int b = idx >> 6, j = idx & 63;
        float s = 0.f;
        for (int e = 0; e < 64; ++e) s += kv[b * 64 + e] * kw1[j * 64 + e];
        tmp1[idx] = s >= 0.f ? s : NEG * s;
    } else if (idx < 1024 + 2048) {         // nfb: (16,128)
        const int t = idx - 1024;
        const int b = t >> 7, c = t & 127;
        float s = nfbias[c];
        for (int e = 0; e < 128; ++e) s += te[b * 128 + e] * nfw[c * 128 + e];
        nfb[t] = s;
    }
}

// kern[(b*C + c)*9 + t] = tmp1[b] . kW2[c*9+t]
__global__ __launch_bounds__(256)
void small2_kernel(const float* __restrict__ tmp1, const float* __restrict__ kw2,
                   float* __restrict__ kern) {
    const int idx = blockIdx.x * 256 + threadIdx.x;    // 18432 total
    if (idx < BB * CC * 9) {
        const int b = idx / 1152, rc = idx % 1152;
        float s = 0.f;
        for (int e = 0; e < 64; ++e) s += tmp1[b * 64 + e] * kw2[rc * 64 + e];
        kern[idx] = s;
    }
}

// ---------------- GroupNorm apply + Swish (elementwise) ----------------
__global__ __launch_bounds__(256)
void gn_apply_kernel(const float* __restrict__ x, const float* __restrict__ gamma,
                     const float* __restrict__ beta, const float* __restrict__ stats,
                     float* __restrict__ hact) {
    const int64_t total4 = (int64_t)BB * CC * HH * WW / 4;
    for (int64_t i = (int64_t)blockIdx.x * 256 + threadIdx.x; i < total4;
         i += (int64_t)gridDim.x * 256) {
        const int64_t e = i * 4;
        const int c = (int)((e >> 14) & (CC - 1));   // H*W = 2^14
        const int b = (int)(e >> 21);                // C*H*W = 2^21
        const int gi = b * GG + (c >> 2);
        const float mean = stats[2 * gi], rstd = stats[2 * gi + 1];
        const float ga = gamma[c] * rstd;
        const float be = beta[c] - mean * ga;
        float4 v = *(const float4*)&x[e];
        float a0 = v.x * ga + be, a1 = v.y * ga + be, a2 = v.z * ga + be, a3 = v.w * ga + be;
        v.x = a0 / (1.f + expf(-a0));
        v.y = a1 / (1.f + expf(-a1));
        v.z = a2 / (1.f + expf(-a2));
        v.w = a3 / (1.f + expf(-a3));
        *(float4*)&hact[e] = v;
    }
}

// ---------------- direct 3x3 conv, 128->128, SAME ----------------
// FINAL=0: out = conv(in) + bias + nfb          (writes hbuf)
// FINAL=1: out = conv(in) + bias + leaky(depthwise(in, kern)) + xres
template <int FINAL>
__global__ __launch_bounds__(256, 3)
void conv3x3_kernel(const float* __restrict__ in, const float* __restrict__ wgt,
                    const float* __restrict__ bias, const float* __restrict__ nfb,
                    const float* __restrict__ kern, const float* __restrict__ xres,
                    float* __restrict__ out) {
    __shared__ float s_in[CK][34][36];     // 39168 B
    __shared__ float s_w[CK][9][COB];      //  4608 B

    const int tid = threadIdx.x;
    const int bid = blockIdx.x;
    const int cb = bid & 7;
    const int tx = (bid >> 3) & 3;
    const int ty = (bid >> 5) & 3;
    const int b  = bid >> 7;
    const int co0 = cb * COB;
    const int x0 = tx * TS, y0 = ty * TS;

    const int g = tid & 7;        // x-group (8 groups of 4 px)
    const int r = tid >> 3;       // row 0..31
    const int xb = g * 4;

    float acc[4][COB];
    #pragma unroll
    for (int p = 0; p < 4; ++p)
        #pragma unroll
        for (int j = 0; j < COB; ++j) acc[p][j] = 0.f;

    for (int ck = 0; ck < CC / CK; ++ck) {
        const int ci0 = ck * CK;
        // stage input chunk: CK x 34 x 34
        for (int i = tid; i < CK * 34 * 34; i += 256) {
            const int ci = i / 1156;
            const int rem = i - ci * 1156;
            const int yy = rem / 34;
            const int xx = rem - yy * 34;
            const int gy = y0 + yy - 1, gx = x0 + xx - 1;
            float v = 0.f;
            if ((unsigned)gy < (unsigned)HH && (unsigned)gx < (unsigned)WW)
                v = in[(((size_t)b * CC + ci0 + ci) * HH + gy) * WW + gx];
            s_in[ci][yy][xx] = v;
        }
        // stage weights: CK x 9 x COB  (global reads coalesced over ci,tap)
        for (int i = tid; i < COB * CK * 9; i += 256) {
            const int co = i / (CK * 9);
            const int rem = i - co * CK * 9;
            const int ci = rem / 9;
            const int tap = rem - ci * 9;
            s_w[ci][tap][co] = wgt[(((size_t)(co0 + co)) * CC + ci0 + ci) * 9 + tap];
        }
        __syncthreads();

        for (int ci = 0; ci < CK; ++ci) {
            #pragma unroll
            for (int dy = 0; dy < 3; ++dy) {
                const float* row = &s_in[ci][r + dy][xb];
                float4 r4 = *(const float4*)row;
                float2 r2 = *(const float2*)(row + 4);
                float rv[6] = { r4.x, r4.y, r4.z, r4.w, r2.x, r2.y };
                #pragma unroll
                for (int dx = 0; dx < 3; ++dx) {
                    const float4* wp = (const float4*)&s_w[ci][dy * 3 + dx][0];
                    const float4 w0 = wp[0], w1 = wp[1], w2 = wp[2], w3 = wp[3];
                    #pragma unroll
                    for (int p = 0; p < 4; ++p) {
                        const float v = rv[p + dx];
                        acc[p][0]  += v * w0.x;  acc[p][1]  += v * w0.y;
                        acc[p][2]  += v * w0.z;  acc[p][3]  += v * w0.w;
                        acc[p][4]  += v * w1.x;  acc[p][5]  += v * w1.y;
                        acc[p][6]  += v * w1.z;  acc[p][7]  += v * w1.w;
                        acc[p][8]  += v * w2.x;  acc[p][9]  += v * w2.y;
                        acc[p][10] += v * w2.z;  acc[p][11] += v * w2.w;
                        acc[p][12] += v * w3.x;  acc[p][13] += v * w3.y;
                        acc[p][14] += v * w3.z;  acc[p][15] += v * w3.w;
                    }
                }
            }
        }
        __syncthreads();
    }

    // bias (+ time-embedding bias for conv1)
    #pragma unroll
    for (int j = 0; j < COB; ++j) {
        float bj = bias[co0 + j];
        if (!FINAL) bj += nfb[b * CC + co0 + j];
        #pragma unroll
        for (int p = 0; p < 4; ++p) acc[p][j] += bj;
    }

    if (FINAL) {
        // dynamic depthwise conv over this block's own 16 channels (2 restage chunks)
        #pragma unroll
        for (int cc = 0; cc < COB / CK; ++cc) {
            const int ci0 = co0 + cc * CK;
            for (int i = tid; i < CK * 34 * 34; i += 256) {
                const int ci = i / 1156;
                const int rem = i - ci * 1156;
                const int yy = rem / 34;
                const int xx = rem - yy * 34;
                const int gy = y0 + yy - 1, gx = x0 + xx - 1;
                float v = 0.f;
                if ((unsigned)gy < (unsigned)HH && (unsigned)gx < (unsigned)WW)
                    v = in[(((size_t)b * CC + ci0 + ci) * HH + gy) * WW + gx];
                s_in[ci][yy][xx] = v;
            }
            __syncthreads();
            #pragma unroll
            for (int cl = 0; cl < CK; ++cl) {
                const int j = cc * CK + cl;
                const float* kp = &kern[((size_t)b * CC + co0 + j) * 9];
                float kw[9];
                #pragma unroll
                for (int t = 0; t < 9; ++t) kw[t] = kp[t];
                #pragma unroll
                for (int p = 0; p < 4; ++p) {
                    float d = 0.f;
                    #pragma unroll
                    for (int dy = 0; dy < 3; ++dy) {
                        const float* rw = &s_in[cl][r + dy][xb + p];
                        d += rw[0] * kw[dy * 3 + 0] + rw[1] * kw[dy * 3 + 1] + rw[2] * kw[dy * 3 + 2];
                    }
                    d = d >= 0.f ? d : NEG * d;
                    acc[p][j] += d;
                }
            }
            __syncthreads();
        }
    }

    // epilogue: vectorized store (+ residual for FINAL)
    const size_t obase = (((size_t)b * CC + co0) * HH + (y0 + r)) * WW + (x0 + xb);
    #pragma unroll
    for (int j = 0; j < COB; ++j) {
        float4 o;
        o.x = acc[0][j]; o.y = acc[1][j]; o.z = acc[2][j]; o.w = acc[3][j];
        if (FINAL) {
            const float4 xr4 = *(const float4*)&xres[obase + (size_t)j * HH * WW];
            o.x += xr4.x; o.y += xr4.y; o.z += xr4.z; o.w += xr4.w;
        }
        *(float4*)&out[obase + (size_t)j * HH * WW] = o;
    }
}

extern "C" void kernel_launch(void* const* d_in, const int* in_sizes, int n_in,
                              void* d_out, int out_size, void* d_ws, size_t ws_size,
                              hipStream_t stream) {
    const float* x        = (const float*)d_in[0];
    const float* te       = (const float*)d_in[1];
    const float* kv       = (const float*)d_in[2];
    const float* gn1_g    = (const float*)d_in[3];
    const float* gn1_b    = (const float*)d_in[4];
    const float* conv1_w  = (const float*)d_in[5];
    const float* conv1_b  = (const float*)d_in[6];
    const float* nf_w     = (const float*)d_in[7];
    const float* nf_b     = (const float*)d_in[8];
    const float* kW1      = (const float*)d_in[9];
    const float* kW2      = (const float*)d_in[10];
    const float* daconv_w = (const float*)d_in[11];
    const float* daconv_b = (const float*)d_in[12];

    float* out = (float*)d_out;

    // workspace layout
    float* stats = (float*)d_ws;                  // 1024
    float* nfb   = stats + 1024;                  // 2048
    float* tmp1  = nfb + 2048;                    // 1024
    float* kern  = tmp1 + 1024;                   // 18432
    float* hbuf  = (float*)((((uintptr_t)(kern + 18432)) + 255) & ~(uintptr_t)255);
    float* hact  = out;                           // reuse d_out for GN/Swish output

    gn_stats_kernel<<<dim3(512), dim3(256), 0, stream>>>(x, stats);
    small1_kernel<<<dim3(12), dim3(256), 0, stream>>>(te, nf_w, nf_b, kv, kW1, nfb, tmp1);
    small2_kernel<<<dim3(72), dim3(256), 0, stream>>>(tmp1, kW2, kern);
    gn_apply_kernel<<<dim3(2048), dim3(256), 0, stream>>>(x, gn1_g, gn1_b, stats, hact);

    // conv1: hbuf = conv3x3(hact) + conv1_b + nfb
    conv3x3_kernel<0><<<dim3(2048), dim3(256), 0, stream>>>(
        hact, conv1_w, conv1_b, nfb, nullptr, nullptr, hbuf);
    // final: out = leaky(depthwise(hbuf,kern)) + conv3x3(hbuf) + daconv_b + x
    conv3x3_kernel<1><<<dim3(2048), dim3(256), 0, stream>>>(
        hbuf, daconv_w, daconv_b, nullptr, kern, x, out);
}

// Round 2
// 480.764 us; speedup vs baseline: 6.3230x; 6.3230x over previous
//
#include <hip/hip_runtime.h>
#include <hip/hip_bf16.h>
#include <math.h>
#include <stdint.h>

typedef unsigned short u16;
typedef __attribute__((ext_vector_type(8))) short bfrag;      // 8 bf16 = 4 VGPR
typedef __attribute__((ext_vector_type(4))) float f32x4;
typedef __attribute__((ext_vector_type(8))) unsigned short u16x8;
typedef __attribute__((ext_vector_type(4))) unsigned short u16x4;

#define BB 16
#define CC 128
#define HH 128
#define WW 128
#define GG 32
#define EPSV 1e-5f
#define NEG 0.1f

__device__ __forceinline__ float bf2f(u16 u) {
    unsigned int x = ((unsigned int)u) << 16;
    return __builtin_bit_cast(float, x);
}
__device__ __forceinline__ u16 f2bf(float f) {   // RNE
    unsigned int x = __builtin_bit_cast(unsigned int, f);
    unsigned int r = x + 0x7fffu + ((x >> 16) & 1u);
    return (u16)(r >> 16);
}
__device__ __forceinline__ void gload_lds16(const void* g, void* l) {
    __builtin_amdgcn_global_load_lds(
        (const __attribute__((address_space(1))) void*)g,
        (__attribute__((address_space(3))) void*)l, 16, 0, 0);
}

// ---------------- GroupNorm statistics: one block per (b,g) ----------------
__global__ __launch_bounds__(256)
void gn_stats_kernel(const float* __restrict__ x, float* __restrict__ stats) {
    const int bg = blockIdx.x;                 // 0..511
    const float* base = x + (size_t)bg * 65536;
    float s1 = 0.f, s2 = 0.f;
    for (int i = threadIdx.x; i < 16384; i += 256) {
        float4 v = *(const float4*)&base[i * 4];
        s1 += v.x + v.y + v.z + v.w;
        s2 += v.x * v.x + v.y * v.y + v.z * v.z + v.w * v.w;
    }
    #pragma unroll
    for (int off = 32; off > 0; off >>= 1) {
        s1 += __shfl_down(s1, off);
        s2 += __shfl_down(s2, off);
    }
    __shared__ float rs[8];
    const int wid = threadIdx.x >> 6, lane = threadIdx.x & 63;
    if (lane == 0) { rs[wid * 2] = s1; rs[wid * 2 + 1] = s2; }
    __syncthreads();
    if (threadIdx.x == 0) {
        s1 = rs[0] + rs[2] + rs[4] + rs[6];
        s2 = rs[1] + rs[3] + rs[5] + rs[7];
        float mean = s1 * (1.f / 65536.f);
        float var  = s2 * (1.f / 65536.f) - mean * mean;
        stats[2 * bg]     = mean;
        stats[2 * bg + 1] = rsqrtf(var + EPSV);
    }
}

// ---------------- weight fp32 [co][ci][9] -> bf16 [tap][co][ci] ------------
__global__ __launch_bounds__(256)
void wconv_kernel(const float* __restrict__ w1, const float* __restrict__ w2,
                  u16* __restrict__ w1t, u16* __restrict__ w2t) {
    int idx = blockIdx.x * 256 + threadIdx.x;      // 147456
    if (idx < 147456) {
        int tap = idx >> 14, rem = idx & 16383;
        int co = rem >> 7, ci = rem & 127;
        int src = (co * 128 + ci) * 9 + tap;
        w1t[idx] = f2bf(w1[src]);
        w2t[idx] = f2bf(w2[src]);
    }
}

// ------- small FCs: biastot = te@nfw^T + nf_b + conv1_b ; tmp1 = leaky(kv@kW1^T)
__global__ __launch_bounds__(256)
void small1_kernel(const float* __restrict__ te, const float* __restrict__ nfw,
                   const float* __restrict__ nfbias, const float* __restrict__ c1b,
                   const float* __restrict__ kv, const float* __restrict__ kw1,
                   float* __restrict__ biastot, float* __restrict__ tmp1) {
    const int idx = blockIdx.x * 256 + threadIdx.x;
    if (idx < 1024) {                       // tmp1: (16,64)
        const int b = idx >> 6, j = idx & 63;
        float s = 0.f;
        for (int e = 0; e < 64; ++e) s += kv[b * 64 + e] * kw1[j * 64 + e];
        tmp1[idx] = s >= 0.f ? s : NEG * s;
    } else if (idx < 1024 + 2048) {         // biastot: (16,128)
        const int t = idx - 1024;
        const int b = t >> 7, c = t & 127;
        float s = nfbias[c] + c1b[c];
        for (int e = 0; e < 128; ++e) s += te[b * 128 + e] * nfw[c * 128 + e];
        biastot[t] = s;
    }
}

__global__ __launch_bounds__(256)
void small2_kernel(const float* __restrict__ tmp1, const float* __restrict__ kw2,
                   float* __restrict__ kern) {
    const int idx = blockIdx.x * 256 + threadIdx.x;    // 18432
    if (idx < BB * CC * 9) {
        const int b = idx / 1152, rc = idx % 1152;
        float s = 0.f;
        for (int e = 0; e < 64; ++e) s += tmp1[b * 64 + e] * kw2[rc * 64 + e];
        kern[idx] = s;
    }
}

// ------- GroupNorm apply + Swish, NCHW fp32 -> NHWC bf16 (LDS transpose) ----
__global__ __launch_bounds__(256)
void gn_apply_kernel(const float* __restrict__ x, const float* __restrict__ gamma,
                     const float* __restrict__ beta, const float* __restrict__ stats,
                     u16* __restrict__ hact) {
    __shared__ u16 s_t[128 * 128];
    const int tid = threadIdx.x;
    const int y = blockIdx.x & 127, b = blockIdx.x >> 7;
    #pragma unroll
    for (int i = 0; i < 16; ++i) {
        int unit = (i << 8) + tid;              // (c, x-quad)
        int c = unit >> 5, xq = unit & 31, xx = xq * 4;
        float4 v = *(const float4*)&x[(((size_t)b * 128 + c) * 128 + y) * 128 + xx];
        int gi = b * 32 + (c >> 2);
        float mean = stats[2 * gi], rstd = stats[2 * gi + 1];
        float ga = gamma[c] * rstd, be = beta[c] - mean * ga;
        float a0 = v.x * ga + be, a1 = v.y * ga + be, a2 = v.z * ga + be, a3 = v.w * ga + be;
        a0 = a0 / (1.f + __expf(-a0)); a1 = a1 / (1.f + __expf(-a1));
        a2 = a2 / (1.f + __expf(-a2)); a3 = a3 / (1.f + __expf(-a3));
        int cs = c ^ ((xq & 15) << 3);          // bank swizzle, keeps 8-groups intact
        s_t[(xx + 0) * 128 + cs] = f2bf(a0);
        s_t[(xx + 1) * 128 + cs] = f2bf(a1);
        s_t[(xx + 2) * 128 + cs] = f2bf(a2);
        s_t[(xx + 3) * 128 + cs] = f2bf(a3);
    }
    __syncthreads();
    #pragma unroll
    for (int i = 0; i < 8; ++i) {
        int unit = (i << 8) + tid;              // (x, c-group)
        int xx = unit >> 4, c0 = (unit & 15) * 8;
        int c0s = c0 ^ (((xx >> 2) & 15) << 3);
        u16x8 v = *(const u16x8*)&s_t[xx * 128 + c0s];
        *(u16x8*)&hact[((((size_t)b * 128 + y) * 128 + xx) * 128) + c0] = v;
    }
}

// ---------------- MFMA implicit-GEMM 3x3 conv, 128->128, SAME --------------
// act: NHWC bf16. wt: [tap][co][ci] bf16.
// FINAL=0: outh(NHWC bf16) = conv(act) + biastot[b][co]
// FINAL=1: outf(NCHW fp32) += conv(act) + bias[co]
template <int FINAL>
__global__ __launch_bounds__(256, 3)
void conv_mfma_kernel(const u16* __restrict__ act, const u16* __restrict__ wt,
                      const float* __restrict__ bias,
                      float* __restrict__ outf, u16* __restrict__ outh) {
    __shared__ u16 s_in[5760];        // [cik(4)][pos(180)][8]  = 11520 B
    __shared__ u16 s_w[2][4096];      // [buf][cik(4)][co(128)][8] = 2*8192 B

    const int tid = threadIdx.x;
    const int lane = tid & 63, wid = tid >> 6;
    const int wm = wid >> 1, wn = wid & 1;
    const int l15 = lane & 15, l4 = lane >> 4;

    const int bid = blockIdx.x;                // 16b x 16ty x 8tx
    const int tx = bid & 7, ty = (bid >> 3) & 15, b = bid >> 7;
    const int x0 = tx * 16, y0 = ty * 8;
    const bool interior = (tx > 0) && (tx < 7) && (ty > 0) && (ty < 15);
    const size_t actbase = (size_t)b * (128 * 128 * 128);

    f32x4 acc[4][4];
    #pragma unroll
    for (int mi = 0; mi < 4; ++mi)
        #pragma unroll
        for (int nj = 0; nj < 4; ++nj) acc[mi][nj] = (f32x4)(0.f);

    auto stage_in = [&](int ci0) {
        #pragma unroll
        for (int r = 0; r < 3; ++r) {
            int L = r * 256 + tid;
            if (L < 720) {
                int cik = L / 180, rem = L % 180;
                int yy = rem / 18, xx = rem - yy * 18;
                int gy = y0 + yy - 1, gx = x0 + xx - 1;
                const u16* src = act + actbase + (((size_t)gy * 128 + gx) * 128 + ci0 + cik * 8);
                if (interior) {
                    u16* dst = &s_in[(size_t)(r * 256 + ((tid >> 6) << 6)) * 8];
                    gload_lds16(src, dst);
                } else {
                    u16x8 v = (u16x8)(u16)0;
                    if ((unsigned)gy < 128u && (unsigned)gx < 128u) v = *(const u16x8*)src;
                    *(u16x8*)&s_in[(size_t)L * 8] = v;
                }
            }
        }
    };
    auto stage_w = [&](int buf, int tap, int ci0) {
        #pragma unroll
        for (int r = 0; r < 2; ++r) {
            int L = r * 256 + tid;
            int cik = L >> 7, co = L & 127;
            const u16* src = wt + (((size_t)tap * 128 + co) * 128 + ci0 + cik * 8);
            u16* dst = &s_w[buf][(size_t)(r * 256 + ((tid >> 6) << 6)) * 8];
            gload_lds16(src, dst);
        }
    };

    stage_in(0);
    stage_w(0, 0, 0);
    __syncthreads();

    for (int chunk = 0; chunk < 4; ++chunk) {
        const int ci0 = chunk * 32;
        for (int tap = 0; tap < 9; ++tap) {
            const int k = chunk * 9 + tap;
            if (k + 1 < 36) {
                int kn = k + 1;
                stage_w(kn & 1, kn % 9, (kn / 9) * 32);
            }
            // ---- compute: 8 ds_read_b128 + 16 MFMA per wave ----
            const int dy = tap / 3, dx = tap - dy * 3;
            const u16* swb = s_w[k & 1];
            bfrag a[4], bv[4];
            #pragma unroll
            for (int mi = 0; mi < 4; ++mi)
                a[mi] = *(const bfrag*)&swb[(l4 * 128 + wm * 64 + mi * 16 + l15) * 8];
            #pragma unroll
            for (int nj = 0; nj < 4; ++nj) {
                int yy = wn * 4 + nj + dy;
                int xx = l15 + dx;
                bv[nj] = *(const bfrag*)&s_in[(l4 * 180 + yy * 18 + xx) * 8];
            }
            #pragma unroll
            for (int mi = 0; mi < 4; ++mi)
                #pragma unroll
                for (int nj = 0; nj < 4; ++nj)
                    acc[mi][nj] = __builtin_amdgcn_mfma_f32_16x16x32_bf16(
                        a[mi], bv[nj], acc[mi][nj], 0, 0, 0);

            if (tap == 8 && chunk < 3) {
                __syncthreads();            // all s_in readers done
                stage_in(ci0 + 32);
                __syncthreads();            // staged s_in + s_w visible
            } else {
                __syncthreads();
            }
        }
    }

    // ---- epilogue ----
    if (!FINAL) {
        const float* bb = bias + b * 128;
        #pragma unroll
        for (int mi = 0; mi < 4; ++mi) {
            const int cb = wm * 64 + mi * 16 + l4 * 4;
            float4 bv4 = *(const float4*)&bb[cb];
            #pragma unroll
            for (int nj = 0; nj < 4; ++nj) {
                int y = y0 + wn * 4 + nj, xx = x0 + l15;
                u16x4 p;
                p[0] = f2bf(acc[mi][nj][0] + bv4.x);
                p[1] = f2bf(acc[mi][nj][1] + bv4.y);
                p[2] = f2bf(acc[mi][nj][2] + bv4.z);
                p[3] = f2bf(acc[mi][nj][3] + bv4.w);
                *(u16x4*)&outh[((((size_t)b * 128 + y) * 128 + xx) * 128) + cb] = p;
            }
        }
    } else {
        #pragma unroll
        for (int mi = 0; mi < 4; ++mi) {
            const int cb = wm * 64 + mi * 16 + l4 * 4;
            float4 bv4 = *(const float4*)&bias[cb];
            #pragma unroll
            for (int nj = 0; nj < 4; ++nj) {
                int y = y0 + wn * 4 + nj, xx = x0 + l15;
                size_t obase = (((size_t)b * 128 + cb) * 128 + y) * 128 + xx;
                outf[obase]           += acc[mi][nj][0] + bv4.x;
                outf[obase + 16384]   += acc[mi][nj][1] + bv4.y;
                outf[obase + 32768]   += acc[mi][nj][2] + bv4.z;
                outf[obase + 49152]   += acc[mi][nj][3] + bv4.w;
            }
        }
    }
}

// ------- dynamic depthwise 3x3 + leaky + x residual -> out NCHW fp32 -------
__global__ __launch_bounds__(256)
void dw_kernel(const u16* __restrict__ hbuf, const float* __restrict__ kern,
               const float* __restrict__ xres, float* __restrict__ outf) {
    __shared__ float s_o[128][129];
    const int tid = threadIdx.x;
    const int y = blockIdx.x & 127, b = blockIdx.x >> 7;
    const int c0 = (tid & 15) * 8;

    float kreg[72];
    {
        const float* kp = kern + ((size_t)b * 128 + c0) * 9;
        #pragma unroll
        for (int t = 0; t < 18; ++t)
            *(float4*)&kreg[t * 4] = *(const float4*)&kp[t * 4];
    }

    #pragma unroll
    for (int i = 0; i < 8; ++i) {
        int u = (i << 8) + tid;
        int xx = u >> 4;
        float a8[8];
        #pragma unroll
        for (int e = 0; e < 8; ++e) a8[e] = 0.f;
        #pragma unroll
        for (int dy = 0; dy < 3; ++dy) {
            int gy = y + dy - 1;
            if ((unsigned)gy >= 128u) continue;
            #pragma unroll
            for (int dx = 0; dx < 3; ++dx) {
                int gx = xx + dx - 1;
                if ((unsigned)gx >= 128u) continue;
                u16x8 h = *(const u16x8*)&hbuf[(((size_t)b * 128 + gy) * 128 + gx) * 128 + c0];
                #pragma unroll
                for (int e = 0; e < 8; ++e)
                    a8[e] += bf2f(h[e]) * kreg[e * 9 + dy * 3 + dx];
            }
        }
        #pragma unroll
        for (int e = 0; e < 8; ++e) {
            float v = a8[e];
            s_o[c0 + e][xx] = v >= 0.f ? v : NEG * v;
        }
    }
    __syncthreads();
    #pragma unroll
    for (int i = 0; i < 16; ++i) {
        int unit = (i << 8) + tid;          // (c, x-quad)
        int c = unit >> 5, x4 = (unit & 31) * 4;
        float4 v = *(const float4*)&s_o[c][x4];
        size_t gi = (((size_t)b * 128 + c) * 128 + y) * 128 + x4;
        float4 xr = *(const float4*)&xres[gi];
        v.x += xr.x; v.y += xr.y; v.z += xr.z; v.w += xr.w;
        *(float4*)&outf[gi] = v;
    }
}

extern "C" void kernel_launch(void* const* d_in, const int* in_sizes, int n_in,
                              void* d_out, int out_size, void* d_ws, size_t ws_size,
                              hipStream_t stream) {
    const float* x        = (const float*)d_in[0];
    const float* te       = (const float*)d_in[1];
    const float* kv       = (const float*)d_in[2];
    const float* gn1_g    = (const float*)d_in[3];
    const float* gn1_b    = (const float*)d_in[4];
    const float* conv1_w  = (const float*)d_in[5];
    const float* conv1_b  = (const float*)d_in[6];
    const float* nf_w     = (const float*)d_in[7];
    const float* nf_b     = (const float*)d_in[8];
    const float* kW1      = (const float*)d_in[9];
    const float* kW2      = (const float*)d_in[10];
    const float* daconv_w = (const float*)d_in[11];
    const float* daconv_b = (const float*)d_in[12];

    float* out = (float*)d_out;

    // workspace (alive across the final kernels): kern, w2t, hbuf
    float* kern  = (float*)d_ws;                         // 18432 f32
    u16*   w2t   = (u16*)(kern + 18432);                 // 147456 u16
    u16*   hbuf  = (u16*)(kern + 92160);                 // 33.5M u16 (67 MB)

    // temps dead before dw_kernel overwrite of d_out: live in d_out upper half
    float* up      = out + 16777216;
    float* stats   = up;                                 // 1024
    float* biastot = up + 1024;                          // 2048
    float* tmp1    = up + 3072;                          // 1024
    u16*   w1t     = (u16*)(up + 4096);                  // 147456 u16
    u16*   hact    = (u16*)out;                          // lower half of d_out

    gn_stats_kernel<<<dim3(512), dim3(256), 0, stream>>>(x, stats);
    wconv_kernel<<<dim3(576), dim3(256), 0, stream>>>(conv1_w, daconv_w, w1t, w2t);
    small1_kernel<<<dim3(12), dim3(256), 0, stream>>>(te, nf_w, nf_b, conv1_b, kv, kW1,
                                                      biastot, tmp1);
    small2_kernel<<<dim3(72), dim3(256), 0, stream>>>(tmp1, kW2, kern);
    gn_apply_kernel<<<dim3(2048), dim3(256), 0, stream>>>(x, gn1_g, gn1_b, stats, hact);

    // conv1: hbuf = conv(hact) + biastot   (NHWC bf16)
    conv_mfma_kernel<0><<<dim3(2048), dim3(256), 0, stream>>>(hact, w1t, biastot, nullptr, hbuf);
    // dw: out = leaky(depthwise(hbuf, kern)) + x   (NCHW fp32, overwrites all of d_out)
    dw_kernel<<<dim3(2048), dim3(256), 0, stream>>>(hbuf, kern, x, out);
    // conv2: out += conv(hbuf) + daconv_b
    conv_mfma_kernel<1><<<dim3(2048), dim3(256), 0, stream>>>(hbuf, w2t, daconv_b, out, nullptr);
}

// Round 3
// 473.965 us; speedup vs baseline: 6.4137x; 1.0143x over previous
//
#include <hip/hip_runtime.h>
#include <hip/hip_bf16.h>
#include <math.h>
#include <stdint.h>

typedef unsigned short u16;
typedef __attribute__((ext_vector_type(8))) short bfrag;      // 8 bf16 = 4 VGPR
typedef __attribute__((ext_vector_type(4))) float f32x4;
typedef __attribute__((ext_vector_type(8))) unsigned short u16x8;
typedef __attribute__((ext_vector_type(4))) unsigned short u16x4;

#define BB 16
#define CC 128
#define HH 128
#define WW 128
#define GG 32
#define EPSV 1e-5f
#define NEG 0.1f

__device__ __forceinline__ float bf2f(u16 u) {
    unsigned int x = ((unsigned int)u) << 16;
    return __builtin_bit_cast(float, x);
}
__device__ __forceinline__ u16 f2bf(float f) {   // RNE
    unsigned int x = __builtin_bit_cast(unsigned int, f);
    unsigned int r = x + 0x7fffu + ((x >> 16) & 1u);
    return (u16)(r >> 16);
}
__device__ __forceinline__ void gload_lds16(const void* g, void* l) {
    __builtin_amdgcn_global_load_lds(
        (const __attribute__((address_space(1))) void*)g,
        (__attribute__((address_space(3))) void*)l, 16, 0, 0);
}

// ---------------- GroupNorm statistics: one block per (b,g) ----------------
__global__ __launch_bounds__(256)
void gn_stats_kernel(const float* __restrict__ x, float* __restrict__ stats) {
    const int bg = blockIdx.x;                 // 0..511
    const float* base = x + (size_t)bg * 65536;
    float s1 = 0.f, s2 = 0.f;
    for (int i = threadIdx.x; i < 16384; i += 256) {
        float4 v = *(const float4*)&base[i * 4];
        s1 += v.x + v.y + v.z + v.w;
        s2 += v.x * v.x + v.y * v.y + v.z * v.z + v.w * v.w;
    }
    #pragma unroll
    for (int off = 32; off > 0; off >>= 1) {
        s1 += __shfl_down(s1, off);
        s2 += __shfl_down(s2, off);
    }
    __shared__ float rs[8];
    const int wid = threadIdx.x >> 6, lane = threadIdx.x & 63;
    if (lane == 0) { rs[wid * 2] = s1; rs[wid * 2 + 1] = s2; }
    __syncthreads();
    if (threadIdx.x == 0) {
        s1 = rs[0] + rs[2] + rs[4] + rs[6];
        s2 = rs[1] + rs[3] + rs[5] + rs[7];
        float mean = s1 * (1.f / 65536.f);
        float var  = s2 * (1.f / 65536.f) - mean * mean;
        stats[2 * bg]     = mean;
        stats[2 * bg + 1] = rsqrtf(var + EPSV);
    }
}

// ------ weight fp32 [co][ci][9] -> bf16 [tap][chunk(4)][co(128)][g(4)][8] ---
// One wave A-frag load (16 co x 32 ci) is then 1KB fully contiguous.
__global__ __launch_bounds__(256)
void wconv_kernel(const float* __restrict__ w1, const float* __restrict__ w2,
                  u16* __restrict__ w1t, u16* __restrict__ w2t) {
    int idx = blockIdx.x * 256 + threadIdx.x;      // 147456
    if (idx < 147456) {
        int e  = idx & 7;
        int g  = (idx >> 3) & 3;
        int co = (idx >> 5) & 127;
        int ck = (idx >> 12) & 3;
        int t  = idx >> 14;
        int src = (co * 128 + (ck * 32 + g * 8 + e)) * 9 + t;
        w1t[idx] = f2bf(w1[src]);
        w2t[idx] = f2bf(w2[src]);
    }
}

// ------- small FCs: biastot = te@nfw^T + nf_b + conv1_b ; tmp1 = leaky(kv@kW1^T)
__global__ __launch_bounds__(256)
void small1_kernel(const float* __restrict__ te, const float* __restrict__ nfw,
                   const float* __restrict__ nfbias, const float* __restrict__ c1b,
                   const float* __restrict__ kv, const float* __restrict__ kw1,
                   float* __restrict__ biastot, float* __restrict__ tmp1) {
    const int idx = blockIdx.x * 256 + threadIdx.x;
    if (idx < 1024) {                       // tmp1: (16,64)
        const int b = idx >> 6, j = idx & 63;
        float s = 0.f;
        for (int e = 0; e < 64; ++e) s += kv[b * 64 + e] * kw1[j * 64 + e];
        tmp1[idx] = s >= 0.f ? s : NEG * s;
    } else if (idx < 1024 + 2048) {         // biastot: (16,128)
        const int t = idx - 1024;
        const int b = t >> 7, c = t & 127;
        float s = nfbias[c] + c1b[c];
        for (int e = 0; e < 128; ++e) s += te[b * 128 + e] * nfw[c * 128 + e];
        biastot[t] = s;
    }
}

__global__ __launch_bounds__(256)
void small2_kernel(const float* __restrict__ tmp1, const float* __restrict__ kw2,
                   float* __restrict__ kern) {
    const int idx = blockIdx.x * 256 + threadIdx.x;    // 18432
    if (idx < BB * CC * 9) {
        const int b = idx / 1152, rc = idx % 1152;
        float s = 0.f;
        for (int e = 0; e < 64; ++e) s += tmp1[b * 64 + e] * kw2[rc * 64 + e];
        kern[idx] = s;
    }
}

// ------- GroupNorm apply + Swish, NCHW fp32 -> NHWC bf16 (LDS transpose) ----
__global__ __launch_bounds__(256)
void gn_apply_kernel(const float* __restrict__ x, const float* __restrict__ gamma,
                     const float* __restrict__ beta, const float* __restrict__ stats,
                     u16* __restrict__ hact) {
    __shared__ u16 s_t[128 * 128];
    const int tid = threadIdx.x;
    const int y = blockIdx.x & 127, b = blockIdx.x >> 7;
    #pragma unroll
    for (int i = 0; i < 16; ++i) {
        int unit = (i << 8) + tid;              // (c, x-quad)
        int c = unit >> 5, xq = unit & 31, xx = xq * 4;
        float4 v = *(const float4*)&x[(((size_t)b * 128 + c) * 128 + y) * 128 + xx];
        int gi = b * 32 + (c >> 2);
        float mean = stats[2 * gi], rstd = stats[2 * gi + 1];
        float ga = gamma[c] * rstd, be = beta[c] - mean * ga;
        float a0 = v.x * ga + be, a1 = v.y * ga + be, a2 = v.z * ga + be, a3 = v.w * ga + be;
        a0 = a0 / (1.f + __expf(-a0)); a1 = a1 / (1.f + __expf(-a1));
        a2 = a2 / (1.f + __expf(-a2)); a3 = a3 / (1.f + __expf(-a3));
        int cs = c ^ ((xq & 15) << 3);          // bank swizzle, keeps 8-groups intact
        s_t[(xx + 0) * 128 + cs] = f2bf(a0);
        s_t[(xx + 1) * 128 + cs] = f2bf(a1);
        s_t[(xx + 2) * 128 + cs] = f2bf(a2);
        s_t[(xx + 3) * 128 + cs] = f2bf(a3);
    }
    __syncthreads();
    #pragma unroll
    for (int i = 0; i < 8; ++i) {
        int unit = (i << 8) + tid;              // (x, c-group)
        int xx = unit >> 4, c0 = (unit & 15) * 8;
        int c0s = c0 ^ (((xx >> 2) & 15) << 3);
        u16x8 v = *(const u16x8*)&s_t[xx * 128 + c0s];
        *(u16x8*)&hact[((((size_t)b * 128 + y) * 128 + xx) * 128) + c0] = v;
    }
}

// ---------------- MFMA implicit-GEMM 3x3 conv, 128->128, SAME --------------
// act: NHWC bf16. wt: [tap][chunk][co][g][8] bf16 (A-frags loaded global->VGPR).
// FINAL=0: outh(NHWC bf16) = conv(act) + biastot[b][co]
// FINAL=1: outf(NCHW fp32) += conv(act) + bias[co]
template <int FINAL>
__global__ __launch_bounds__(256, 3)
void conv_mfma_kernel(const u16* __restrict__ act, const u16* __restrict__ wt,
                      const float* __restrict__ bias,
                      float* __restrict__ outf, u16* __restrict__ outh) {
    __shared__ __align__(16) u16 s_in[2][5760];   // [buf][cik(4)][pos(180)][8] = 23 KB

    const int tid = threadIdx.x;
    const int lane = tid & 63, wid = tid >> 6;
    const int wm = wid >> 1, wn = wid & 1;
    const int l15 = lane & 15, l4 = lane >> 4;

    const int bid = blockIdx.x;                // 16b x 16ty x 8tx
    const int tx = bid & 7, ty = (bid >> 3) & 15, b = bid >> 7;
    const int x0 = tx * 16, y0 = ty * 8;
    const bool interior = (tx > 0) && (tx < 7) && (ty > 0) && (ty < 15);
    const size_t actbase = (size_t)b * (128 * 128 * 128);

    f32x4 acc[4][4];
    #pragma unroll
    for (int mi = 0; mi < 4; ++mi)
        #pragma unroll
        for (int nj = 0; nj < 4; ++nj) acc[mi][nj] = (f32x4)(0.f);

    auto stage_in = [&](int buf, int ci0) {
        #pragma unroll
        for (int r = 0; r < 3; ++r) {
            int L = r * 256 + tid;
            if (L < 720) {
                int cik = L / 180, rem = L % 180;
                int yy = rem / 18, xx = rem - yy * 18;
                int gy = y0 + yy - 1, gx = x0 + xx - 1;
                const u16* src = act + actbase + (((size_t)gy * 128 + gx) * 128 + ci0 + cik * 8);
                if (interior) {
                    u16* dst = &s_in[buf][(size_t)(r * 256 + ((tid >> 6) << 6)) * 8];
                    gload_lds16(src, dst);
                } else {
                    u16x8 v = (u16x8)(u16)0;
                    if ((unsigned)gy < 128u && (unsigned)gx < 128u) v = *(const u16x8*)src;
                    *(u16x8*)&s_in[buf][(size_t)L * 8] = v;
                }
            }
        }
    };

    stage_in(0, 0);
    __syncthreads();

    // per-thread invariant offsets
    const int bbase = (l4 * 180 + (wn * 4) * 18 + l15) * 8;    // u16 index into s_in[buf]
    const u16* wlane = wt + ((size_t)(wm * 64 + l15)) * 32 + l4 * 8;

    int cur = 0;
    for (int chunk = 0; chunk < 4; ++chunk) {
        if (chunk < 3) stage_in(cur ^ 1, (chunk + 1) * 32);

        const u16* sb = &s_in[cur][0];
        #pragma unroll
        for (int tap = 0; tap < 9; ++tap) {
            const int dy = tap / 3, dx = tap - dy * 3;
            // A: 4 coalesced 1KB global loads (L1/L2-resident weights)
            const u16* wp = wlane + (size_t)(tap * 4 + chunk) * 4096;
            bfrag a0 = *(const bfrag*)(wp);
            bfrag a1 = *(const bfrag*)(wp + 512);
            bfrag a2 = *(const bfrag*)(wp + 1024);
            bfrag a3 = *(const bfrag*)(wp + 1536);
            // B: 4 ds_read_b128 at immediate offsets
            const int bo = bbase + (dy * 18 + dx) * 8;
            bfrag b0 = *(const bfrag*)&sb[bo];
            bfrag b1 = *(const bfrag*)&sb[bo + 144];
            bfrag b2 = *(const bfrag*)&sb[bo + 288];
            bfrag b3 = *(const bfrag*)&sb[bo + 432];

            acc[0][0] = __builtin_amdgcn_mfma_f32_16x16x32_bf16(a0, b0, acc[0][0], 0, 0, 0);
            acc[0][1] = __builtin_amdgcn_mfma_f32_16x16x32_bf16(a0, b1, acc[0][1], 0, 0, 0);
            acc[0][2] = __builtin_amdgcn_mfma_f32_16x16x32_bf16(a0, b2, acc[0][2], 0, 0, 0);
            acc[0][3] = __builtin_amdgcn_mfma_f32_16x16x32_bf16(a0, b3, acc[0][3], 0, 0, 0);
            acc[1][0] = __builtin_amdgcn_mfma_f32_16x16x32_bf16(a1, b0, acc[1][0], 0, 0, 0);
            acc[1][1] = __builtin_amdgcn_mfma_f32_16x16x32_bf16(a1, b1, acc[1][1], 0, 0, 0);
            acc[1][2] = __builtin_amdgcn_mfma_f32_16x16x32_bf16(a1, b2, acc[1][2], 0, 0, 0);
            acc[1][3] = __builtin_amdgcn_mfma_f32_16x16x32_bf16(a1, b3, acc[1][3], 0, 0, 0);
            acc[2][0] = __builtin_amdgcn_mfma_f32_16x16x32_bf16(a2, b0, acc[2][0], 0, 0, 0);
            acc[2][1] = __builtin_amdgcn_mfma_f32_16x16x32_bf16(a2, b1, acc[2][1], 0, 0, 0);
            acc[2][2] = __builtin_amdgcn_mfma_f32_16x16x32_bf16(a2, b2, acc[2][2], 0, 0, 0);
            acc[2][3] = __builtin_amdgcn_mfma_f32_16x16x32_bf16(a2, b3, acc[2][3], 0, 0, 0);
            acc[3][0] = __builtin_amdgcn_mfma_f32_16x16x32_bf16(a3, b0, acc[3][0], 0, 0, 0);
            acc[3][1] = __builtin_amdgcn_mfma_f32_16x16x32_bf16(a3, b1, acc[3][1], 0, 0, 0);
            acc[3][2] = __builtin_amdgcn_mfma_f32_16x16x32_bf16(a3, b2, acc[3][2], 0, 0, 0);
            acc[3][3] = __builtin_amdgcn_mfma_f32_16x16x32_bf16(a3, b3, acc[3][3], 0, 0, 0);
        }
        __syncthreads();     // drains stage_in prefetch; all readers of cur done
        cur ^= 1;
    }

    // ---- epilogue ----
    if (!FINAL) {
        const float* bb = bias + b * 128;
        #pragma unroll
        for (int mi = 0; mi < 4; ++mi) {
            const int cb = wm * 64 + mi * 16 + l4 * 4;
            float4 bv4 = *(const float4*)&bb[cb];
            #pragma unroll
            for (int nj = 0; nj < 4; ++nj) {
                int y = y0 + wn * 4 + nj, xx = x0 + l15;
                u16x4 p;
                p[0] = f2bf(acc[mi][nj][0] + bv4.x);
                p[1] = f2bf(acc[mi][nj][1] + bv4.y);
                p[2] = f2bf(acc[mi][nj][2] + bv4.z);
                p[3] = f2bf(acc[mi][nj][3] + bv4.w);
                *(u16x4*)&outh[((((size_t)b * 128 + y) * 128 + xx) * 128) + cb] = p;
            }
        }
    } else {
        #pragma unroll
        for (int mi = 0; mi < 4; ++mi) {
            const int cb = wm * 64 + mi * 16 + l4 * 4;
            float4 bv4 = *(const float4*)&bias[cb];
            #pragma unroll
            for (int nj = 0; nj < 4; ++nj) {
                int y = y0 + wn * 4 + nj, xx = x0 + l15;
                size_t obase = (((size_t)b * 128 + cb) * 128 + y) * 128 + xx;
                outf[obase]           += acc[mi][nj][0] + bv4.x;
                outf[obase + 16384]   += acc[mi][nj][1] + bv4.y;
                outf[obase + 32768]   += acc[mi][nj][2] + bv4.z;
                outf[obase + 49152]   += acc[mi][nj][3] + bv4.w;
            }
        }
    }
}

// ------- dynamic depthwise 3x3 + leaky + x residual -> out NCHW fp32 -------
__global__ __launch_bounds__(256)
void dw_kernel(const u16* __restrict__ hbuf, const float* __restrict__ kern,
               const float* __restrict__ xres, float* __restrict__ outf) {
    __shared__ float s_o[128][129];
    const int tid = threadIdx.x;
    const int y = blockIdx.x & 127, b = blockIdx.x >> 7;
    const int c0 = (tid & 15) * 8;

    float kreg[72];
    {
        const float* kp = kern + ((size_t)b * 128 + c0) * 9;
        #pragma unroll
        for (int t = 0; t < 18; ++t)
            *(float4*)&kreg[t * 4] = *(const float4*)&kp[t * 4];
    }

    #pragma unroll
    for (int i = 0; i < 8; ++i) {
        int u = (i << 8) + tid;
        int xx = u >> 4;
        float a8[8];
        #pragma unroll
        for (int e = 0; e < 8; ++e) a8[e] = 0.f;
        #pragma unroll
        for (int dy = 0; dy < 3; ++dy) {
            int gy = y + dy - 1;
            if ((unsigned)gy >= 128u) continue;
            #pragma unroll
            for (int dx = 0; dx < 3; ++dx) {
                int gx = xx + dx - 1;
                if ((unsigned)gx >= 128u) continue;
                u16x8 h = *(const u16x8*)&hbuf[(((size_t)b * 128 + gy) * 128 + gx) * 128 + c0];
                #pragma unroll
                for (int e = 0; e < 8; ++e)
                    a8[e] += bf2f(h[e]) * kreg[e * 9 + dy * 3 + dx];
            }
        }
        #pragma unroll
        for (int e = 0; e < 8; ++e) {
            float v = a8[e];
            s_o[c0 + e][xx] = v >= 0.f ? v : NEG * v;
        }
    }
    __syncthreads();
    #pragma unroll
    for (int i = 0; i < 16; ++i) {
        int unit = (i << 8) + tid;          // (c, x-quad)
        int c = unit >> 5, x4 = (unit & 31) * 4;
        float4 v = *(const float4*)&s_o[c][x4];
        size_t gi = (((size_t)b * 128 + c) * 128 + y) * 128 + x4;
        float4 xr = *(const float4*)&xres[gi];
        v.x += xr.x; v.y += xr.y; v.z += xr.z; v.w += xr.w;
        *(float4*)&outf[gi] = v;
    }
}

extern "C" void kernel_launch(void* const* d_in, const int* in_sizes, int n_in,
                              void* d_out, int out_size, void* d_ws, size_t ws_size,
                              hipStream_t stream) {
    const float* x        = (const float*)d_in[0];
    const float* te       = (const float*)d_in[1];
    const float* kv       = (const float*)d_in[2];
    const float* gn1_g    = (const float*)d_in[3];
    const float* gn1_b    = (const float*)d_in[4];
    const float* conv1_w  = (const float*)d_in[5];
    const float* conv1_b  = (const float*)d_in[6];
    const float* nf_w     = (const float*)d_in[7];
    const float* nf_b     = (const float*)d_in[8];
    const float* kW1      = (const float*)d_in[9];
    const float* kW2      = (const float*)d_in[10];
    const float* daconv_w = (const float*)d_in[11];
    const float* daconv_b = (const float*)d_in[12];

    float* out = (float*)d_out;

    // workspace (alive across the final kernels): kern, w2t, hbuf
    float* kern  = (float*)d_ws;                         // 18432 f32
    u16*   w2t   = (u16*)(kern + 18432);                 // 147456 u16
    u16*   hbuf  = (u16*)(kern + 92160);                 // 33.5M u16 (67 MB)

    // temps dead before dw_kernel overwrite of d_out: live in d_out upper half
    float* up      = out + 16777216;
    float* stats   = up;                                 // 1024
    float* biastot = up + 1024;                          // 2048
    float* tmp1    = up + 3072;                          // 1024
    u16*   w1t     = (u16*)(up + 4096);                  // 147456 u16
    u16*   hact    = (u16*)out;                          // lower half of d_out

    gn_stats_kernel<<<dim3(512), dim3(256), 0, stream>>>(x, stats);
    wconv_kernel<<<dim3(576), dim3(256), 0, stream>>>(conv1_w, daconv_w, w1t, w2t);
    small1_kernel<<<dim3(12), dim3(256), 0, stream>>>(te, nf_w, nf_b, conv1_b, kv, kW1,
                                                      biastot, tmp1);
    small2_kernel<<<dim3(72), dim3(256), 0, stream>>>(tmp1, kW2, kern);
    gn_apply_kernel<<<dim3(2048), dim3(256), 0, stream>>>(x, gn1_g, gn1_b, stats, hact);

    // conv1: hbuf = conv(hact) + biastot   (NHWC bf16)
    conv_mfma_kernel<0><<<dim3(2048), dim3(256), 0, stream>>>(hact, w1t, biastot, nullptr, hbuf);
    // dw: out = leaky(depthwise(hbuf, kern)) + x   (NCHW fp32, overwrites all of d_out)
    dw_kernel<<<dim3(2048), dim3(256), 0, stream>>>(hbuf, kern, x, out);
    // conv2: out += conv(hbuf) + daconv_b
    conv_mfma_kernel<1><<<dim3(2048), dim3(256), 0, stream>>>(hbuf, w2t, daconv_b, out, nullptr);
}